// Round 8
// baseline (248.877 us; speedup 1.0000x reference)
//
#include <hip/hip_runtime.h>
#include <hip/hip_bf16.h>
#include <stdint.h>

#define N_PTS   8192
#define D       256
#define N_E     8192
#define BETA    0.25f
#define EPS_1   1.0000001f   // 1 + 1e-7 (rounds to 1+ulp in f32, same as jnp)

typedef unsigned long long u64;
typedef __attribute__((ext_vector_type(8)))  short bf16x8;   // 8 bf16 = 4 VGPR
typedef __attribute__((ext_vector_type(8)))  short short8;
typedef __attribute__((ext_vector_type(16))) float f32x16;

// ---- workspace layout (bytes) ----
// Fragment-linear bf16 arrays for 32x32x16 MFMA: element (p,k) of an
// 8192x256 matrix lives at
//   fi = (p>>5)*16 + (k>>4);  l = (p&31) + 32*((k&15)>>3);  j = k&7
//   idx = fi*512 + l*8 + j
// Each 32x16 MFMA fragment is a contiguous 1KB block in lane-major order:
// global_load_lds(uniform base + lane*16) and ds_read_b128(lane*16) are both
// perfectly linear -> zero bank conflicts (verified R3-R7: conflicts = 0).
#define WS_KEYS   0
#define WS_COUNTS (N_PTS * 8)                    // 64 KB
#define WS_LOSS   (WS_COUNTS + N_E * 4)          // +32 KB
#define WS_AHI    (1 << 20)                      // 1 MB-aligned
#define WS_ALO    (WS_AHI + N_PTS * D * 2)
#define WS_BHI    (WS_ALO + N_PTS * D * 2)
#define WS_BLO    (WS_BHI + N_E * D * 2)         // total ~17 MB

__device__ __forceinline__ short f2bf(float x) {
    __hip_bfloat16 h = __float2bfloat16(x);      // RTN-even
    return *reinterpret_cast<short*>(&h);
}
__device__ __forceinline__ float bf2f(short s) {
    __hip_bfloat16 h = *reinterpret_cast<__hip_bfloat16*>(&s);
    return __bfloat162float(h);
}

#define GLOAD16(gp, lp) __builtin_amdgcn_global_load_lds(                      \
    (const __attribute__((address_space(1))) void*)(gp),                       \
    (__attribute__((address_space(3))) void*)(lp), 16, 0, 0)

// ------- init + split f32 -> bf16 hi/lo, fragment-linear (32x16 frags) ------
__global__ __launch_bounds__(256) void k_prep(
    const float* __restrict__ u, const float* __restrict__ cb,
    short* __restrict__ Ahi, short* __restrict__ Alo,
    short* __restrict__ Bhi, short* __restrict__ Blo,
    u64* __restrict__ keys, float* __restrict__ counts,
    double* __restrict__ loss_sum)
{
    const int tid = blockIdx.x * 256 + threadIdx.x;   // 0 .. 262143
    if (tid < N_E)   counts[tid] = 0.f;
    if (tid < N_PTS) keys[tid] = ~0ULL;
    if (tid == 0)    *loss_sum = 0.0;

    const int fi = tid >> 6;             // fragment index (p>>5)*16 + (k>>4)
    const int l  = tid & 63;
    const int p  = (fi >> 4) * 32 + (l & 31);
    const int k  = (fi & 15) * 16 + (l >> 5) * 8;
    const size_t gin  = (size_t)p * D + k;
    const size_t gout = (size_t)tid * 8;

    float v[8];
    short8 h8, l8;

    *(float4*)&v[0] = *(const float4*)&u[gin];
    *(float4*)&v[4] = *(const float4*)&u[gin + 4];
    if (k == 0) v[0] = -v[0];            // Minkowski sign fold on time comp
    #pragma unroll
    for (int j = 0; j < 8; ++j) {
        h8[j] = f2bf(v[j]);
        l8[j] = f2bf(v[j] - bf2f(h8[j]));
    }
    *(short8*)&Ahi[gout] = h8;
    *(short8*)&Alo[gout] = l8;

    *(float4*)&v[0] = *(const float4*)&cb[gin];
    *(float4*)&v[4] = *(const float4*)&cb[gin + 4];
    #pragma unroll
    for (int j = 0; j < 8; ++j) {
        h8[j] = f2bf(v[j]);
        l8[j] = f2bf(v[j] - bf2f(h8[j]));
    }
    *(short8*)&Bhi[gout] = h8;
    *(short8*)&Blo[gout] = l8;
}

// ---------------- MFMA argmin: C = A~ . B^T, per-row argmin, no C write ------
// split-bf16: a.b = ahi.bhi + ahi.blo + alo.bhi  (err ~2^-18 rel, safe margin)
// 128x128 tile, 4 waves (2x2 of 64x64), 32x32x16 MFMA.
// TRUE T4 pipeline: TWO DISTINCT static __shared__ objects + fully unrolled
// K-loop so every stage/read references its buffer STATICALLY. This lets
// alias analysis prove the pending global_load_lds DMA (-> smY) cannot alias
// the ds_reads (-> smX), so the compiler does NOT insert its own
// s_waitcnt vmcnt(0); the counted vmcnt(8) is the only VMEM wait and each
// tile's loads stay in flight across a full MFMA phase. (R7's runtime-indexed
// single object sm[2][..] provoked an implicit vmcnt(0) -> R6-identical perf.)
#define BMM 128
#define BNN 128
#define NKS 8                // K-tiles of 32 (= 2 fragment-columns each)

typedef short lds_buf_t[4][8 * 512];     // 32 KB: Ahi,Alo,Bhi,Blo slices

__device__ __forceinline__ void stage_tile(
    const short* __restrict__ gsrc, lds_buf_t& wbuf,
    int w, int l, int eb, int kt)
{
    #pragma unroll
    for (int i = 0; i < 8; ++i)
        GLOAD16(gsrc + ((size_t)(eb + (i >> 1)) * 16 + kt * 2 + (i & 1)) * 512
                     + l * 8,
                &wbuf[w][i * 512]);
}

__device__ __forceinline__ void compute_tile(
    lds_buf_t& rbuf, int wr, int wc, int l, f32x16 acc[2][2])
{
    #pragma unroll
    for (int kf = 0; kf < 2; ++kf) {
        bf16x8 ah[2], al[2], bh[2], bl[2];
        #pragma unroll
        for (int m = 0; m < 2; ++m) {
            ah[m] = *(const bf16x8*)&rbuf[0][((wr * 2 + m) * 2 + kf) * 512 + l * 8];
            al[m] = *(const bf16x8*)&rbuf[1][((wr * 2 + m) * 2 + kf) * 512 + l * 8];
            bh[m] = *(const bf16x8*)&rbuf[2][((wc * 2 + m) * 2 + kf) * 512 + l * 8];
            bl[m] = *(const bf16x8*)&rbuf[3][((wc * 2 + m) * 2 + kf) * 512 + l * 8];
        }
        // same-acc MFMAs spaced 4 apart (>= 8-cyc issue of 32x32 shape)
        __builtin_amdgcn_s_setprio(1);
        #pragma unroll
        for (int m = 0; m < 2; ++m)
            #pragma unroll
            for (int n = 0; n < 2; ++n)
                acc[m][n] = __builtin_amdgcn_mfma_f32_32x32x16_bf16(
                    ah[m], bh[n], acc[m][n], 0, 0, 0);
        #pragma unroll
        for (int m = 0; m < 2; ++m)
            #pragma unroll
            for (int n = 0; n < 2; ++n)
                acc[m][n] = __builtin_amdgcn_mfma_f32_32x32x16_bf16(
                    ah[m], bl[n], acc[m][n], 0, 0, 0);
        #pragma unroll
        for (int m = 0; m < 2; ++m)
            #pragma unroll
            for (int n = 0; n < 2; ++n)
                acc[m][n] = __builtin_amdgcn_mfma_f32_32x32x16_bf16(
                    al[m], bh[n], acc[m][n], 0, 0, 0);
        __builtin_amdgcn_s_setprio(0);
    }
}

__global__ __launch_bounds__(256, 2) void k_argmin_mfma(
    const short* __restrict__ Ahi, const short* __restrict__ Alo,
    const short* __restrict__ Bhi, const short* __restrict__ Blo,
    u64* __restrict__ keys)
{
    __shared__ short sm0[4][8 * 512];    // 32 KB buffer 0 (distinct object)
    __shared__ short sm1[4][8 * 512];    // 32 KB buffer 1 (distinct object)

    const int t   = threadIdx.x;
    const int w   = t >> 6;              // wave 0..3
    const int l   = t & 63;
    // natural order (R4-verified locality: FETCH 37 MB, L2-resident panels)
    const int rb  = blockIdx.x >> 6;     // 64 row-panels (points)
    const int cbk = blockIdx.x & 63;     // 64 col-panels (codes)
    const int r0  = rb * BMM, c0 = cbk * BNN;
    const int wr  = w >> 1, wc = w & 1;  // 2x2 wave grid, 64x64 each

    const short* gsrc = (w == 0) ? Ahi : (w == 1) ? Alo : (w == 2) ? Bhi : Blo;
    const int eb = ((w < 2) ? rb : cbk) * 4;   // entity-fragment base

    f32x16 acc[2][2];
    #pragma unroll
    for (int i = 0; i < 2; ++i)
        #pragma unroll
        for (int j = 0; j < 2; ++j)
            #pragma unroll
            for (int r = 0; r < 16; ++r) acc[i][j][r] = 0.f;

    // prologue: issue K-tile 0 into sm0
    stage_tile(gsrc, sm0, w, l, eb, 0);

    // fully unrolled pipeline; vmcnt never drains to 0 until the last tile
#define TILE_STEP(RB, WB, KT, LAST)                                            \
    {                                                                          \
        if (!(LAST)) {                                                         \
            stage_tile(gsrc, WB, w, l, eb, (KT) + 1);                          \
            asm volatile("s_waitcnt vmcnt(8)" ::: "memory");                   \
        } else {                                                               \
            asm volatile("s_waitcnt vmcnt(0)" ::: "memory");                   \
        }                                                                      \
        __builtin_amdgcn_s_barrier();                                          \
        compute_tile(RB, wr, wc, l, acc);                                      \
        __builtin_amdgcn_s_barrier();                                          \
    }

    TILE_STEP(sm0, sm1, 0, false)
    TILE_STEP(sm1, sm0, 1, false)
    TILE_STEP(sm0, sm1, 2, false)
    TILE_STEP(sm1, sm0, 3, false)
    TILE_STEP(sm0, sm1, 4, false)
    TILE_STEP(sm1, sm0, 5, false)
    TILE_STEP(sm0, sm1, 6, false)
    TILE_STEP(sm1, sm0, 7, true)
#undef TILE_STEP

    // epilogue: per-row argmin over this block's 128 codes, then atomicMin
    // 32x32 C/D layout (m74/m101-verified):
    //   col = lane&31, row = (reg&3) + 8*(reg>>2) + 4*(lane>>5)
    const int ch = l & 31;               // column within 32-frag
    #pragma unroll
    for (int m = 0; m < 2; ++m) {
        #pragma unroll
        for (int r = 0; r < 16; ++r) {
            u64 km = ~0ULL;
            #pragma unroll
            for (int n = 0; n < 2; ++n) {
                float mm = fmaxf(-acc[m][n][r], EPS_1);    // m >= 1 > 0
                unsigned code = (unsigned)(c0 + wc * 64 + n * 32 + ch);
                u64 key = ((u64)__float_as_uint(mm) << 32) | code;
                km = key < km ? key : km;
            }
            #pragma unroll
            for (int s = 16; s >= 1; s >>= 1) {            // 32-lane halves
                u64 o = __shfl_xor(km, s);
                km = o < km ? o : km;
            }
            if (ch == 0) {
                const int row = r0 + wr * 64 + m * 32 +
                                (r & 3) + 8 * (r >> 2) + 4 * (l >> 5);
                atomicMin(&keys[row], km);
            }
        }
    }
}

// ---------------- gather z_q, per-pair f32 distance, histogram ----------------
__global__ __launch_bounds__(256) void k_gather(
    const float* __restrict__ u, const float* __restrict__ cb,
    const u64* __restrict__ keys, float* __restrict__ out,
    float* __restrict__ counts, double* __restrict__ loss_sum)
{
    __shared__ float sred[4];
    const int t    = threadIdx.x;
    const int w    = t >> 6;
    const int row  = blockIdx.x * 4 + w;
    const int lane = t & 63;
    const u64 key  = keys[row];
    const int idx  = (int)(unsigned)(key & 0xffffffffULL);

    float* zq = out + 1;
    float4 uv = *(const float4*)&u[(size_t)row * D + lane * 4];
    float4 cv = *(const float4*)&cb[(size_t)idx * D + lane * 4];
    if (lane == 0) uv.x = -uv.x;                  // Lorentzian sign
    float partial = uv.x * cv.x + uv.y * cv.y + uv.z * cv.z + uv.w * cv.w;
    *(float4*)&zq[(size_t)row * D + lane * 4] = cv;

    #pragma unroll
    for (int s = 32; s >= 1; s >>= 1)
        partial += __shfl_xor(partial, s);

    if (lane == 0) {
        float m = fmaxf(-partial, EPS_1);
        sred[w] = acoshf(m);
        atomicAdd(&counts[idx], 1.f);             // scattered: low contention
    }
    __syncthreads();
    if (t == 0)                                   // 1 f64 atomic per block
        atomicAdd(loss_sum, (double)(sred[0] + sred[1] + sred[2] + sred[3]));
}

// ---------------- scalars: loss, perplexity, entropy, e_mean -----------------
__global__ __launch_bounds__(256) void k_final(
    const float* __restrict__ counts, const double* __restrict__ loss_sum,
    float* __restrict__ out)
{
    __shared__ float red[256];
    const int t = threadIdx.x;
    const int OFF_P = 1 + N_PTS * D;
    float ent = 0.f;
    for (int i = t; i < N_E; i += 256) {
        float e = counts[i] * (1.0f / N_PTS);
        out[OFF_P + 2 + i] = e;
        ent -= e * logf(e + 1e-10f);
    }
    red[t] = ent;
    __syncthreads();
    for (int s = 128; s > 0; s >>= 1) {
        if (t < s) red[t] += red[t + s];
        __syncthreads();
    }
    if (t == 0) {
        float entropy = red[0];
        out[0]         = (1.0f + BETA) * (float)(*loss_sum / (double)N_PTS);
        out[OFF_P]     = expf(entropy);
        out[OFF_P + 1] = entropy;
    }
}

// ---------------- launch ----------------
extern "C" void kernel_launch(void* const* d_in, const int* in_sizes, int n_in,
                              void* d_out, int out_size, void* d_ws, size_t ws_size,
                              hipStream_t stream)
{
    const float* u  = (const float*)d_in[0];
    const float* cb = (const float*)d_in[1];
    float* out = (float*)d_out;
    char* ws = (char*)d_ws;

    u64*    keys     = (u64*)(ws + WS_KEYS);
    float*  counts   = (float*)(ws + WS_COUNTS);
    double* loss_sum = (double*)(ws + WS_LOSS);
    short*  Ahi = (short*)(ws + WS_AHI);
    short*  Alo = (short*)(ws + WS_ALO);
    short*  Bhi = (short*)(ws + WS_BHI);
    short*  Blo = (short*)(ws + WS_BLO);

    k_prep<<<N_PTS * D / 8 / 256, 256, 0, stream>>>(u, cb, Ahi, Alo, Bhi, Blo,
                                                    keys, counts, loss_sum);
    k_argmin_mfma<<<(N_PTS / BMM) * (N_E / BNN), 256, 0, stream>>>(
        Ahi, Alo, Bhi, Blo, keys);
    k_gather<<<N_PTS / 4, 256, 0, stream>>>(u, cb, keys, out, counts, loss_sum);
    k_final<<<1, 256, 0, stream>>>(counts, loss_sum, out);
}

// Round 9
// 219.147 us; speedup vs baseline: 1.1357x; 1.1357x over previous
//
#include <hip/hip_runtime.h>
#include <hip/hip_bf16.h>
#include <stdint.h>

#define N_PTS   8192
#define D       256
#define N_E     8192
#define BETA    0.25f
#define EPS_1   1.0000001f   // 1 + 1e-7 (rounds to 1+ulp in f32, same as jnp)

typedef unsigned long long u64;
typedef __attribute__((ext_vector_type(8)))  short bf16x8;   // 8 bf16 = 4 VGPR
typedef __attribute__((ext_vector_type(8)))  short short8;
typedef __attribute__((ext_vector_type(16))) float f32x16;

// ---- workspace layout (bytes) ----
// Fragment-linear bf16 arrays for 32x32x16 MFMA: element (p,k) of an
// 8192x256 matrix lives at
//   fi = (p>>5)*16 + (k>>4);  l = (p&31) + 32*((k&15)>>3);  j = k&7
//   idx = fi*512 + l*8 + j
// Each 32x16 MFMA fragment is a contiguous 1KB block in lane-major order:
// global_load_lds(uniform base + lane*16) and ds_read_b128(lane*16) are both
// perfectly linear -> zero bank conflicts (verified R3-R8: conflicts = 0).
#define WS_KEYS   0
#define WS_COUNTS (N_PTS * 8)                    // 64 KB
#define WS_LOSS   (WS_COUNTS + N_E * 4)          // +32 KB
#define WS_AHI    (1 << 20)                      // 1 MB-aligned
#define WS_ALO    (WS_AHI + N_PTS * D * 2)
#define WS_BHI    (WS_ALO + N_PTS * D * 2)
#define WS_BLO    (WS_BHI + N_E * D * 2)         // total ~17 MB

__device__ __forceinline__ short f2bf(float x) {
    __hip_bfloat16 h = __float2bfloat16(x);      // RTN-even
    return *reinterpret_cast<short*>(&h);
}
__device__ __forceinline__ float bf2f(short s) {
    __hip_bfloat16 h = *reinterpret_cast<__hip_bfloat16*>(&s);
    return __bfloat162float(h);
}

#define GLOAD16(gp, lp) __builtin_amdgcn_global_load_lds(                      \
    (const __attribute__((address_space(1))) void*)(gp),                       \
    (__attribute__((address_space(3))) void*)(lp), 16, 0, 0)

// ------- init + split f32 -> bf16 hi/lo, fragment-linear (32x16 frags) ------
__global__ __launch_bounds__(256) void k_prep(
    const float* __restrict__ u, const float* __restrict__ cb,
    short* __restrict__ Ahi, short* __restrict__ Alo,
    short* __restrict__ Bhi, short* __restrict__ Blo,
    u64* __restrict__ keys, float* __restrict__ counts,
    double* __restrict__ loss_sum)
{
    const int tid = blockIdx.x * 256 + threadIdx.x;   // 0 .. 262143
    if (tid < N_E)   counts[tid] = 0.f;
    if (tid < N_PTS) keys[tid] = ~0ULL;
    if (tid == 0)    *loss_sum = 0.0;

    const int fi = tid >> 6;             // fragment index (p>>5)*16 + (k>>4)
    const int l  = tid & 63;
    const int p  = (fi >> 4) * 32 + (l & 31);
    const int k  = (fi & 15) * 16 + (l >> 5) * 8;
    const size_t gin  = (size_t)p * D + k;
    const size_t gout = (size_t)tid * 8;

    float v[8];
    short8 h8, l8;

    *(float4*)&v[0] = *(const float4*)&u[gin];
    *(float4*)&v[4] = *(const float4*)&u[gin + 4];
    if (k == 0) v[0] = -v[0];            // Minkowski sign fold on time comp
    #pragma unroll
    for (int j = 0; j < 8; ++j) {
        h8[j] = f2bf(v[j]);
        l8[j] = f2bf(v[j] - bf2f(h8[j]));
    }
    *(short8*)&Ahi[gout] = h8;
    *(short8*)&Alo[gout] = l8;

    *(float4*)&v[0] = *(const float4*)&cb[gin];
    *(float4*)&v[4] = *(const float4*)&cb[gin + 4];
    #pragma unroll
    for (int j = 0; j < 8; ++j) {
        h8[j] = f2bf(v[j]);
        l8[j] = f2bf(v[j] - bf2f(h8[j]));
    }
    *(short8*)&Bhi[gout] = h8;
    *(short8*)&Blo[gout] = l8;
}

// ---------------- MFMA argmin: C = A~ . B^T, per-row argmin, no C write ------
// split-bf16: a.b = ahi.bhi + ahi.blo + alo.bhi  (err ~2^-18 rel, safe margin)
// 256x256 tile (KEY CHANGE vs R4-R8's 128x128: halves L2 staging traffic,
// 1 GB -> 512 MB, which R4-R8 counters show was the real wall: MfmaUtil x dur
// == 44 us MFMA work in every round; staging exceeded it at 128^2).
// 8 waves 2(M)x4(N), per-wave 128x64 (acc 4x2 f32x16 = 128 VGPR), 32x32x16
// MFMA, static double-buffered 2x64 KB LDS, counted-vmcnt prefetch.
// Per block per K-step: stage 64 KB (~1200 cyc L2) < MFMA 3072 cyc -> staging
// now fits under compute even if partially serialized.
#define BMM 256
#define BNN 256
#define NKS 8                // K-tiles of 32 (= 2 fragment-columns each)

typedef short lds_buf_t[4][16 * 512];    // 64 KB: Ahi,Alo,Bhi,Blo slices

__device__ __forceinline__ void stage_tile(
    const short* __restrict__ gsrc, lds_buf_t& wbuf,
    int a, int h, int l, int eb, int kt)
{
    // wave stages its array a, row-half h: frags rf = h*4..h*4+3, kf = 0..1
    #pragma unroll
    for (int i = 0; i < 8; ++i) {
        const int rf = h * 4 + (i >> 1);
        const int kf = i & 1;
        GLOAD16(gsrc + ((size_t)(eb + rf) * 16 + kt * 2 + kf) * 512 + l * 8,
                &wbuf[a][(rf * 2 + kf) * 512]);
    }
}

__device__ __forceinline__ void compute_tile(
    lds_buf_t& rbuf, int wr, int wc, int l, f32x16 acc[4][2])
{
    #pragma unroll
    for (int kf = 0; kf < 2; ++kf) {
        bf16x8 ah[4], al[4], bh[2], bl[2];
        #pragma unroll
        for (int m = 0; m < 4; ++m) {
            ah[m] = *(const bf16x8*)&rbuf[0][((wr * 4 + m) * 2 + kf) * 512 + l * 8];
            al[m] = *(const bf16x8*)&rbuf[1][((wr * 4 + m) * 2 + kf) * 512 + l * 8];
        }
        #pragma unroll
        for (int n = 0; n < 2; ++n) {
            bh[n] = *(const bf16x8*)&rbuf[2][((wc * 2 + n) * 2 + kf) * 512 + l * 8];
            bl[n] = *(const bf16x8*)&rbuf[3][((wc * 2 + n) * 2 + kf) * 512 + l * 8];
        }
        // same-acc MFMAs spaced 8 apart (>= 8-cyc CU-wide issue of 32x32)
        __builtin_amdgcn_s_setprio(1);
        #pragma unroll
        for (int m = 0; m < 4; ++m)
            #pragma unroll
            for (int n = 0; n < 2; ++n)
                acc[m][n] = __builtin_amdgcn_mfma_f32_32x32x16_bf16(
                    ah[m], bh[n], acc[m][n], 0, 0, 0);
        #pragma unroll
        for (int m = 0; m < 4; ++m)
            #pragma unroll
            for (int n = 0; n < 2; ++n)
                acc[m][n] = __builtin_amdgcn_mfma_f32_32x32x16_bf16(
                    ah[m], bl[n], acc[m][n], 0, 0, 0);
        #pragma unroll
        for (int m = 0; m < 4; ++m)
            #pragma unroll
            for (int n = 0; n < 2; ++n)
                acc[m][n] = __builtin_amdgcn_mfma_f32_32x32x16_bf16(
                    al[m], bh[n], acc[m][n], 0, 0, 0);
        __builtin_amdgcn_s_setprio(0);
    }
}

__global__ __launch_bounds__(512, 2) void k_argmin_mfma(
    const short* __restrict__ Ahi, const short* __restrict__ Alo,
    const short* __restrict__ Bhi, const short* __restrict__ Blo,
    u64* __restrict__ keys)
{
    __shared__ short sm0[4][16 * 512];   // 64 KB buffer 0 (distinct object)
    __shared__ short sm1[4][16 * 512];   // 64 KB buffer 1 (distinct object)

    const int t   = threadIdx.x;
    const int w   = t >> 6;              // wave 0..7
    const int l   = t & 63;
    // natural rb-major order: one rb-row of 32 blocks shares the A panel
    // (hot in every XCD L2); each XCD keeps its B residue class (~1MB) warm.
    const int rb  = blockIdx.x >> 5;     // 32 row-panels (points)
    const int cbk = blockIdx.x & 31;     // 32 col-panels (codes)
    const int r0  = rb * BMM, c0 = cbk * BNN;
    const int wr  = w >> 2, wc = w & 3;  // 2x4 wave grid, 128x64 each

    const int a   = w & 3;               // staging: array per wave
    const int h   = w >> 2;              // row-half per wave
    const short* gsrc = (a == 0) ? Ahi : (a == 1) ? Alo : (a == 2) ? Bhi : Blo;
    const int eb = ((a < 2) ? rb : cbk) * 8;   // entity fragment-row base

    f32x16 acc[4][2];
    #pragma unroll
    for (int i = 0; i < 4; ++i)
        #pragma unroll
        for (int j = 0; j < 2; ++j)
            #pragma unroll
            for (int r = 0; r < 16; ++r) acc[i][j][r] = 0.f;

    // prologue: issue K-tile 0 into sm0
    stage_tile(gsrc, sm0, a, h, l, eb, 0);

    // fully unrolled pipeline; vmcnt never drains to 0 until the last tile
#define TILE_STEP(RB, WB, KT, LAST)                                            \
    {                                                                          \
        if (!(LAST)) {                                                         \
            stage_tile(gsrc, WB, a, h, l, eb, (KT) + 1);                       \
            asm volatile("s_waitcnt vmcnt(8)" ::: "memory");                   \
        } else {                                                               \
            asm volatile("s_waitcnt vmcnt(0)" ::: "memory");                   \
        }                                                                      \
        __builtin_amdgcn_s_barrier();                                          \
        compute_tile(RB, wr, wc, l, acc);                                      \
        __builtin_amdgcn_s_barrier();                                          \
    }

    TILE_STEP(sm0, sm1, 0, false)
    TILE_STEP(sm1, sm0, 1, false)
    TILE_STEP(sm0, sm1, 2, false)
    TILE_STEP(sm1, sm0, 3, false)
    TILE_STEP(sm0, sm1, 4, false)
    TILE_STEP(sm1, sm0, 5, false)
    TILE_STEP(sm0, sm1, 6, false)
    TILE_STEP(sm1, sm0, 7, true)
#undef TILE_STEP

    // epilogue: per-row argmin over this block's 256 codes, then atomicMin
    // 32x32 C/D layout (m74/m101-verified):
    //   col = lane&31, row = (reg&3) + 8*(reg>>2) + 4*(lane>>5)
    const int ch = l & 31;               // column within 32-frag
    #pragma unroll
    for (int m = 0; m < 4; ++m) {
        #pragma unroll
        for (int r = 0; r < 16; ++r) {
            u64 km = ~0ULL;
            #pragma unroll
            for (int n = 0; n < 2; ++n) {
                float mm = fmaxf(-acc[m][n][r], EPS_1);    // m >= 1 > 0
                unsigned code = (unsigned)(c0 + wc * 64 + n * 32 + ch);
                u64 key = ((u64)__float_as_uint(mm) << 32) | code;
                km = key < km ? key : km;
            }
            #pragma unroll
            for (int s = 16; s >= 1; s >>= 1) {            // 32-lane halves
                u64 o = __shfl_xor(km, s);
                km = o < km ? o : km;
            }
            if (ch == 0) {
                const int row = r0 + wr * 128 + m * 32 +
                                (r & 3) + 8 * (r >> 2) + 4 * (l >> 5);
                atomicMin(&keys[row], km);
            }
        }
    }
}

// ---------------- gather z_q, per-pair f32 distance, histogram ----------------
__global__ __launch_bounds__(256) void k_gather(
    const float* __restrict__ u, const float* __restrict__ cb,
    const u64* __restrict__ keys, float* __restrict__ out,
    float* __restrict__ counts, double* __restrict__ loss_sum)
{
    __shared__ float sred[4];
    const int t    = threadIdx.x;
    const int w    = t >> 6;
    const int row  = blockIdx.x * 4 + w;
    const int lane = t & 63;
    const u64 key  = keys[row];
    const int idx  = (int)(unsigned)(key & 0xffffffffULL);

    float* zq = out + 1;
    float4 uv = *(const float4*)&u[(size_t)row * D + lane * 4];
    float4 cv = *(const float4*)&cb[(size_t)idx * D + lane * 4];
    if (lane == 0) uv.x = -uv.x;                  // Lorentzian sign
    float partial = uv.x * cv.x + uv.y * cv.y + uv.z * cv.z + uv.w * cv.w;
    *(float4*)&zq[(size_t)row * D + lane * 4] = cv;

    #pragma unroll
    for (int s = 32; s >= 1; s >>= 1)
        partial += __shfl_xor(partial, s);

    if (lane == 0) {
        float m = fmaxf(-partial, EPS_1);
        sred[w] = acoshf(m);
        atomicAdd(&counts[idx], 1.f);             // scattered: low contention
    }
    __syncthreads();
    if (t == 0)                                   // 1 f64 atomic per block
        atomicAdd(loss_sum, (double)(sred[0] + sred[1] + sred[2] + sred[3]));
}

// ---------------- scalars: loss, perplexity, entropy, e_mean -----------------
__global__ __launch_bounds__(256) void k_final(
    const float* __restrict__ counts, const double* __restrict__ loss_sum,
    float* __restrict__ out)
{
    __shared__ float red[256];
    const int t = threadIdx.x;
    const int OFF_P = 1 + N_PTS * D;
    float ent = 0.f;
    for (int i = t; i < N_E; i += 256) {
        float e = counts[i] * (1.0f / N_PTS);
        out[OFF_P + 2 + i] = e;
        ent -= e * logf(e + 1e-10f);
    }
    red[t] = ent;
    __syncthreads();
    for (int s = 128; s > 0; s >>= 1) {
        if (t < s) red[t] += red[t + s];
        __syncthreads();
    }
    if (t == 0) {
        float entropy = red[0];
        out[0]         = (1.0f + BETA) * (float)(*loss_sum / (double)N_PTS);
        out[OFF_P]     = expf(entropy);
        out[OFF_P + 1] = entropy;
    }
}

// ---------------- launch ----------------
extern "C" void kernel_launch(void* const* d_in, const int* in_sizes, int n_in,
                              void* d_out, int out_size, void* d_ws, size_t ws_size,
                              hipStream_t stream)
{
    const float* u  = (const float*)d_in[0];
    const float* cb = (const float*)d_in[1];
    float* out = (float*)d_out;
    char* ws = (char*)d_ws;

    u64*    keys     = (u64*)(ws + WS_KEYS);
    float*  counts   = (float*)(ws + WS_COUNTS);
    double* loss_sum = (double*)(ws + WS_LOSS);
    short*  Ahi = (short*)(ws + WS_AHI);
    short*  Alo = (short*)(ws + WS_ALO);
    short*  Bhi = (short*)(ws + WS_BHI);
    short*  Blo = (short*)(ws + WS_BLO);

    k_prep<<<N_PTS * D / 8 / 256, 256, 0, stream>>>(u, cb, Ahi, Alo, Bhi, Blo,
                                                    keys, counts, loss_sum);
    k_argmin_mfma<<<(N_PTS / BMM) * (N_E / BNN), 512, 0, stream>>>(
        Ahi, Alo, Bhi, Blo, keys);
    k_gather<<<N_PTS / 4, 256, 0, stream>>>(u, cb, keys, out, counts, loss_sum);
    k_final<<<1, 256, 0, stream>>>(counts, loss_sum, out);
}

// Round 10
// 203.143 us; speedup vs baseline: 1.2251x; 1.0788x over previous
//
#include <hip/hip_runtime.h>
#include <hip/hip_bf16.h>
#include <stdint.h>

#define N_PTS   8192
#define D       256
#define N_E     8192
#define BETA    0.25f
#define EPS_1   1.0000001f   // 1 + 1e-7 (rounds to 1+ulp in f32, same as jnp)

typedef unsigned long long u64;
typedef __attribute__((ext_vector_type(8)))  short bf16x8;   // 8 bf16 = 4 VGPR
typedef __attribute__((ext_vector_type(8)))  short short8;
typedef __attribute__((ext_vector_type(16))) float f32x16;

// ---- workspace layout (bytes) ----
// Fragment-linear bf16 arrays for 32x32x16 MFMA: element (p,k) of an
// 8192x256 matrix lives at
//   fi = (p>>5)*16 + (k>>4);  l = (p&31) + 32*((k&15)>>3);  j = k&7
//   idx = fi*512 + l*8 + j
// Each 32x16 MFMA fragment is a contiguous 1KB block in lane-major order:
// global_load_lds(uniform base + lane*16) and ds_read_b128(lane*16) are both
// perfectly linear -> zero bank conflicts (verified R3-R9: conflicts = 0).
#define WS_KEYS   0
#define WS_COUNTS (N_PTS * 8)                    // 64 KB
#define WS_LOSS   (WS_COUNTS + N_E * 4)          // +32 KB
#define WS_AHI    (1 << 20)                      // 1 MB-aligned
#define WS_ALO    (WS_AHI + N_PTS * D * 2)
#define WS_BHI    (WS_ALO + N_PTS * D * 2)
#define WS_BLO    (WS_BHI + N_E * D * 2)         // total ~17 MB

__device__ __forceinline__ short f2bf(float x) {
    __hip_bfloat16 h = __float2bfloat16(x);      // RTN-even
    return *reinterpret_cast<short*>(&h);
}
__device__ __forceinline__ float bf2f(short s) {
    __hip_bfloat16 h = *reinterpret_cast<__hip_bfloat16*>(&s);
    return __bfloat162float(h);
}

#define GLOAD16(gp, lp) __builtin_amdgcn_global_load_lds(                      \
    (const __attribute__((address_space(1))) void*)(gp),                       \
    (__attribute__((address_space(3))) void*)(lp), 16, 0, 0)

// DPP f32 min step: x = min(x, x[dpp-perm(lane)]); pure VALU, no DS pipe.
#define DPP_MIN(x, ctrl)                                                       \
    x = fminf(x, __int_as_float(__builtin_amdgcn_update_dpp(                   \
            __float_as_int(x), __float_as_int(x), (ctrl), 0xF, 0xF, true)))

// ------- init + split f32 -> bf16 hi/lo, fragment-linear (32x16 frags) ------
__global__ __launch_bounds__(256) void k_prep(
    const float* __restrict__ u, const float* __restrict__ cb,
    short* __restrict__ Ahi, short* __restrict__ Alo,
    short* __restrict__ Bhi, short* __restrict__ Blo,
    u64* __restrict__ keys, float* __restrict__ counts,
    double* __restrict__ loss_sum)
{
    const int tid = blockIdx.x * 256 + threadIdx.x;   // 0 .. 262143
    if (tid < N_E)   counts[tid] = 0.f;
    if (tid < N_PTS) keys[tid] = ~0ULL;
    if (tid == 0)    *loss_sum = 0.0;

    const int fi = tid >> 6;             // fragment index (p>>5)*16 + (k>>4)
    const int l  = tid & 63;
    const int p  = (fi >> 4) * 32 + (l & 31);
    const int k  = (fi & 15) * 16 + (l >> 5) * 8;
    const size_t gin  = (size_t)p * D + k;
    const size_t gout = (size_t)tid * 8;

    float v[8];
    short8 h8, l8;

    *(float4*)&v[0] = *(const float4*)&u[gin];
    *(float4*)&v[4] = *(const float4*)&u[gin + 4];
    if (k == 0) v[0] = -v[0];            // Minkowski sign fold on time comp
    #pragma unroll
    for (int j = 0; j < 8; ++j) {
        h8[j] = f2bf(v[j]);
        l8[j] = f2bf(v[j] - bf2f(h8[j]));
    }
    *(short8*)&Ahi[gout] = h8;
    *(short8*)&Alo[gout] = l8;

    *(float4*)&v[0] = *(const float4*)&cb[gin];
    *(float4*)&v[4] = *(const float4*)&cb[gin + 4];
    #pragma unroll
    for (int j = 0; j < 8; ++j) {
        h8[j] = f2bf(v[j]);
        l8[j] = f2bf(v[j] - bf2f(h8[j]));
    }
    *(short8*)&Bhi[gout] = h8;
    *(short8*)&Blo[gout] = l8;
}

// ---------------- MFMA argmin: C = A~ . B^T, per-row argmin, no C write ------
// split-bf16: a.b = ahi.bhi + ahi.blo + alo.bhi  (err ~2^-18 rel, safe margin)
// 256x256 tile, 8 waves 2(M)x4(N), 32x32x16 MFMA, static double-buffered
// 2x64 KB LDS, counted-vmcnt prefetch (R9 structure, unchanged this round).
// NEW (R10): DPP epilogue -- the R5-R9 u64 shuffle-reduce was 1280
// ds_bpermute_b32 per wave at the block tail, fully exposed at 1 block/CU.
#define BMM 256
#define BNN 256
#define NKS 8                // K-tiles of 32 (= 2 fragment-columns each)

typedef short lds_buf_t[4][16 * 512];    // 64 KB: Ahi,Alo,Bhi,Blo slices

__device__ __forceinline__ void stage_tile(
    const short* __restrict__ gsrc, lds_buf_t& wbuf,
    int a, int h, int l, int eb, int kt)
{
    // wave stages its array a, row-half h: frags rf = h*4..h*4+3, kf = 0..1
    #pragma unroll
    for (int i = 0; i < 8; ++i) {
        const int rf = h * 4 + (i >> 1);
        const int kf = i & 1;
        GLOAD16(gsrc + ((size_t)(eb + rf) * 16 + kt * 2 + kf) * 512 + l * 8,
                &wbuf[a][(rf * 2 + kf) * 512]);
    }
}

__device__ __forceinline__ void compute_tile(
    lds_buf_t& rbuf, int wr, int wc, int l, f32x16 acc[4][2])
{
    #pragma unroll
    for (int kf = 0; kf < 2; ++kf) {
        bf16x8 ah[4], al[4], bh[2], bl[2];
        #pragma unroll
        for (int m = 0; m < 4; ++m) {
            ah[m] = *(const bf16x8*)&rbuf[0][((wr * 4 + m) * 2 + kf) * 512 + l * 8];
            al[m] = *(const bf16x8*)&rbuf[1][((wr * 4 + m) * 2 + kf) * 512 + l * 8];
        }
        #pragma unroll
        for (int n = 0; n < 2; ++n) {
            bh[n] = *(const bf16x8*)&rbuf[2][((wc * 2 + n) * 2 + kf) * 512 + l * 8];
            bl[n] = *(const bf16x8*)&rbuf[3][((wc * 2 + n) * 2 + kf) * 512 + l * 8];
        }
        // same-acc MFMAs spaced 8 apart (>= 8-cyc CU-wide issue of 32x32)
        __builtin_amdgcn_s_setprio(1);
        #pragma unroll
        for (int m = 0; m < 4; ++m)
            #pragma unroll
            for (int n = 0; n < 2; ++n)
                acc[m][n] = __builtin_amdgcn_mfma_f32_32x32x16_bf16(
                    ah[m], bh[n], acc[m][n], 0, 0, 0);
        #pragma unroll
        for (int m = 0; m < 4; ++m)
            #pragma unroll
            for (int n = 0; n < 2; ++n)
                acc[m][n] = __builtin_amdgcn_mfma_f32_32x32x16_bf16(
                    ah[m], bl[n], acc[m][n], 0, 0, 0);
        #pragma unroll
        for (int m = 0; m < 4; ++m)
            #pragma unroll
            for (int n = 0; n < 2; ++n)
                acc[m][n] = __builtin_amdgcn_mfma_f32_32x32x16_bf16(
                    al[m], bh[n], acc[m][n], 0, 0, 0);
        __builtin_amdgcn_s_setprio(0);
    }
}

__global__ __launch_bounds__(512, 2) void k_argmin_mfma(
    const short* __restrict__ Ahi, const short* __restrict__ Alo,
    const short* __restrict__ Bhi, const short* __restrict__ Blo,
    u64* __restrict__ keys)
{
    __shared__ short sm0[4][16 * 512];   // 64 KB buffer 0 (distinct object)
    __shared__ short sm1[4][16 * 512];   // 64 KB buffer 1 (distinct object)

    const int t   = threadIdx.x;
    const int w   = t >> 6;              // wave 0..7
    const int l   = t & 63;
    // natural rb-major order: one rb-row of 32 blocks shares the A panel
    // (hot in every XCD L2); each XCD keeps its B residue class (~1MB) warm.
    const int rb  = blockIdx.x >> 5;     // 32 row-panels (points)
    const int cbk = blockIdx.x & 31;     // 32 col-panels (codes)
    const int r0  = rb * BMM, c0 = cbk * BNN;
    const int wr  = w >> 2, wc = w & 3;  // 2x4 wave grid, 128x64 each

    const int a   = w & 3;               // staging: array per wave
    const int h   = w >> 2;              // row-half per wave
    const short* gsrc = (a == 0) ? Ahi : (a == 1) ? Alo : (a == 2) ? Bhi : Blo;
    const int eb = ((a < 2) ? rb : cbk) * 8;   // entity fragment-row base

    f32x16 acc[4][2];
    #pragma unroll
    for (int i = 0; i < 4; ++i)
        #pragma unroll
        for (int j = 0; j < 2; ++j)
            #pragma unroll
            for (int r = 0; r < 16; ++r) acc[i][j][r] = 0.f;

    // prologue: issue K-tile 0 into sm0
    stage_tile(gsrc, sm0, a, h, l, eb, 0);

    // fully unrolled pipeline; vmcnt never drains to 0 until the last tile
#define TILE_STEP(RB, WB, KT, LAST)                                            \
    {                                                                          \
        if (!(LAST)) {                                                         \
            stage_tile(gsrc, WB, a, h, l, eb, (KT) + 1);                       \
            asm volatile("s_waitcnt vmcnt(8)" ::: "memory");                   \
        } else {                                                               \
            asm volatile("s_waitcnt vmcnt(0)" ::: "memory");                   \
        }                                                                      \
        __builtin_amdgcn_s_barrier();                                          \
        compute_tile(RB, wr, wc, l, acc);                                      \
        __builtin_amdgcn_s_barrier();                                          \
    }

    TILE_STEP(sm0, sm1, 0, false)
    TILE_STEP(sm1, sm0, 1, false)
    TILE_STEP(sm0, sm1, 2, false)
    TILE_STEP(sm1, sm0, 3, false)
    TILE_STEP(sm0, sm1, 4, false)
    TILE_STEP(sm1, sm0, 5, false)
    TILE_STEP(sm0, sm1, 6, false)
    TILE_STEP(sm1, sm0, 7, true)
#undef TILE_STEP

    // ---- DPP epilogue (R10): per-row argmin with ZERO u64 shuffles ----
    // Value-only f32 min across the 32 col-lanes: 4 DPP steps (VALU pipe)
    // + one 32-bit shfl_xor(16); then every lane holding the row-min fires
    // the u64 atomicMin (ties resolved by (value,code) order == np.argmin).
    // 32x32 C/D layout (m74/m101-verified):
    //   col = lane&31, row = (reg&3) + 8*(reg>>2) + 4*(lane>>5)
    const int ch = l & 31;
    const int hi = l >> 5;
    #pragma unroll
    for (int m = 0; m < 4; ++m) {
        const int rowbase = r0 + wr * 128 + m * 32 + 4 * hi;
        #pragma unroll
        for (int r = 0; r < 16; ++r) {
            float m0 = fmaxf(-acc[m][0][r], EPS_1);
            float m1 = fmaxf(-acc[m][1][r], EPS_1);
            float mm = fminf(m0, m1);
            // tie (m0==m1) keeps n=0 -> lower code, matching np.argmin
            unsigned code = (unsigned)(c0 + wc * 64 + (m1 < m0 ? 32 : 0) + ch);
            float mv = mm;
            DPP_MIN(mv, 0xB1);           // quad_perm [1,0,3,2]  (xor 1)
            DPP_MIN(mv, 0x4E);           // quad_perm [2,3,0,1]  (xor 2)
            DPP_MIN(mv, 0x141);          // row_half_mirror      (8-group)
            DPP_MIN(mv, 0x140);          // row_mirror           (16-group)
            mv = fminf(mv, __shfl_xor(mv, 16));   // cross-16 within the row
            if (mm == mv) {
                const int row = rowbase + (r & 3) + 8 * (r >> 2);
                u64 key = ((u64)__float_as_uint(mm) << 32) | code;
                atomicMin(&keys[row], key);
            }
        }
    }
}

// ---------------- gather z_q, per-pair f32 distance, histogram ----------------
__global__ __launch_bounds__(256) void k_gather(
    const float* __restrict__ u, const float* __restrict__ cb,
    const u64* __restrict__ keys, float* __restrict__ out,
    float* __restrict__ counts, double* __restrict__ loss_sum)
{
    __shared__ float sred[4];
    const int t    = threadIdx.x;
    const int w    = t >> 6;
    const int row  = blockIdx.x * 4 + w;
    const int lane = t & 63;
    const u64 key  = keys[row];
    const int idx  = (int)(unsigned)(key & 0xffffffffULL);

    float* zq = out + 1;
    float4 uv = *(const float4*)&u[(size_t)row * D + lane * 4];
    float4 cv = *(const float4*)&cb[(size_t)idx * D + lane * 4];
    if (lane == 0) uv.x = -uv.x;                  // Lorentzian sign
    float partial = uv.x * cv.x + uv.y * cv.y + uv.z * cv.z + uv.w * cv.w;
    *(float4*)&zq[(size_t)row * D + lane * 4] = cv;

    #pragma unroll
    for (int s = 32; s >= 1; s >>= 1)
        partial += __shfl_xor(partial, s);

    if (lane == 0) {
        float m = fmaxf(-partial, EPS_1);
        sred[w] = acoshf(m);
        atomicAdd(&counts[idx], 1.f);             // scattered: low contention
    }
    __syncthreads();
    if (t == 0)                                   // 1 f64 atomic per block
        atomicAdd(loss_sum, (double)(sred[0] + sred[1] + sred[2] + sred[3]));
}

// ---------------- scalars: loss, perplexity, entropy, e_mean -----------------
__global__ __launch_bounds__(256) void k_final(
    const float* __restrict__ counts, const double* __restrict__ loss_sum,
    float* __restrict__ out)
{
    __shared__ float red[256];
    const int t = threadIdx.x;
    const int OFF_P = 1 + N_PTS * D;
    float ent = 0.f;
    for (int i = t; i < N_E; i += 256) {
        float e = counts[i] * (1.0f / N_PTS);
        out[OFF_P + 2 + i] = e;
        ent -= e * logf(e + 1e-10f);
    }
    red[t] = ent;
    __syncthreads();
    for (int s = 128; s > 0; s >>= 1) {
        if (t < s) red[t] += red[t + s];
        __syncthreads();
    }
    if (t == 0) {
        float entropy = red[0];
        out[0]         = (1.0f + BETA) * (float)(*loss_sum / (double)N_PTS);
        out[OFF_P]     = expf(entropy);
        out[OFF_P + 1] = entropy;
    }
}

// ---------------- launch ----------------
extern "C" void kernel_launch(void* const* d_in, const int* in_sizes, int n_in,
                              void* d_out, int out_size, void* d_ws, size_t ws_size,
                              hipStream_t stream)
{
    const float* u  = (const float*)d_in[0];
    const float* cb = (const float*)d_in[1];
    float* out = (float*)d_out;
    char* ws = (char*)d_ws;

    u64*    keys     = (u64*)(ws + WS_KEYS);
    float*  counts   = (float*)(ws + WS_COUNTS);
    double* loss_sum = (double*)(ws + WS_LOSS);
    short*  Ahi = (short*)(ws + WS_AHI);
    short*  Alo = (short*)(ws + WS_ALO);
    short*  Bhi = (short*)(ws + WS_BHI);
    short*  Blo = (short*)(ws + WS_BLO);

    k_prep<<<N_PTS * D / 8 / 256, 256, 0, stream>>>(u, cb, Ahi, Alo, Bhi, Blo,
                                                    keys, counts, loss_sum);
    k_argmin_mfma<<<(N_PTS / BMM) * (N_E / BNN), 512, 0, stream>>>(
        Ahi, Alo, Bhi, Blo, keys);
    k_gather<<<N_PTS / 4, 256, 0, stream>>>(u, cb, keys, out, counts, loss_sum);
    k_final<<<1, 256, 0, stream>>>(counts, loss_sum, out);
}